// Round 4
// baseline (2090.608 us; speedup 1.0000x reference)
//
#include <hip/hip_runtime.h>
#include <math.h>

// Problem constants
#define HD    1024      // hidden size
#define SEQL  512       // sequence length
#define NLAB  122       // labels
#define NWG   256       // workgroups in persistent recurrent kernel (1 per CU)
#define JPW   4         // h-columns (j) per workgroup  (NWG*JPW == HD)

// Workspace layout (bytes). Total ≈ 27.3 MB.
#define OFF_MSG   ((size_t)0)          // h msg: 2*1024 u64 (tag<<32|h_bits)    = 16384 B
#define OFF_HALL  ((size_t)16384)      // h_all: 512*1024 fp32                  = 2097152 B
#define OFF_GATES ((size_t)2113536)    // gates_x: 512*4096 fp32 (swizzled)     = 8388608 B
#define OFF_WR    ((size_t)10502144)   // W_r2: 4096*1024 fp32 (swizzled)       = 16777216 B
// end = 27279360

// ---------------------------------------------------------------------------
// Prep: W_r2 laid out as [g][i][tid] float4 so lstm_rec stages LDS with
// perfectly coalesced global loads and lane-contiguous ds_writes.
//   thread tid of WG g: row = tid&15 (gate=row>>2, jj=row&3), kq = tid>>4
//   w4[i] (= W_lds[i][tid]) must be W_r[R][k..k+3], k = 64*i + 4*kq,
//   R = gate*1024 + g*4 + jj,  W_r[R][k] = W_ih[R][4096+k] + W_hh[R][k]
__global__ __launch_bounds__(256) void prep_wr(const float* __restrict__ W_ih,
                                               const float* __restrict__ W_hh,
                                               float* __restrict__ W_r2) {
    int o = blockIdx.x * 256 + threadIdx.x;   // output float4 index, < 1048576
    int g   = o >> 12;
    int i   = (o >> 8) & 15;
    int t   = o & 255;
    int row = t & 15;
    int kq  = t >> 4;
    int gate = row >> 2;
    int jj   = row & 3;
    int R = (gate << 10) + (g << 2) + jj;
    int k = (i << 6) + (kq << 2);
    float4 wa = *(const float4*)(W_ih + (size_t)R * 5120 + 4096 + k);
    float4 wb = *(const float4*)(W_hh + (size_t)R * 1024 + k);
    float4 out;
    out.x = wa.x + wb.x; out.y = wa.y + wb.y; out.z = wa.z + wb.z; out.w = wa.w + wb.w;
    *(float4*)(W_r2 + (size_t)o * 4) = out;
}

// ---------------------------------------------------------------------------
// gates_x[t][g*16 + gate*4 + jj] = b[r] + sum_k feats[t][k] * W_ih[r][k]
// feats[t] = concat(x[t] (2048), hi[t] (2048)). 64x64 tile, BK=16, fp32 VALU.
__global__ __launch_bounds__(256) void gates_gemm(const float* __restrict__ x,
                                                  const float* __restrict__ hi,
                                                  const float* __restrict__ W_ih,
                                                  const float* __restrict__ b_ih,
                                                  const float* __restrict__ b_hh,
                                                  float* __restrict__ gates_x) {
    __shared__ float As[16][68];
    __shared__ float Bs[16][68];
    const int tid = threadIdx.x;
    const int r0 = blockIdx.x * 64;
    const int t0 = blockIdx.y * 64;
    const int tx = tid & 15, ty = tid >> 4;
    const int l   = tid & 63;
    const int kq4 = tid >> 6;

    float acc[4][4] = {};
    for (int kb = 0; kb < 4096; kb += 16) {
        int k = kb + kq4 * 4;
        const float* asrc = (k < 2048) ? (x  + (size_t)(t0 + l) * 2048 + k)
                                       : (hi + (size_t)(t0 + l) * 2048 + (k - 2048));
        float4 a4 = *(const float4*)asrc;
        float4 b4 = *(const float4*)(W_ih + (size_t)(r0 + l) * 5120 + k);
        __syncthreads();
        As[kq4 * 4 + 0][l] = a4.x; As[kq4 * 4 + 1][l] = a4.y;
        As[kq4 * 4 + 2][l] = a4.z; As[kq4 * 4 + 3][l] = a4.w;
        Bs[kq4 * 4 + 0][l] = b4.x; Bs[kq4 * 4 + 1][l] = b4.y;
        Bs[kq4 * 4 + 2][l] = b4.z; Bs[kq4 * 4 + 3][l] = b4.w;
        __syncthreads();
        #pragma unroll
        for (int kk = 0; kk < 16; ++kk) {
            float4 av = *(const float4*)&As[kk][ty * 4];
            float4 bv = *(const float4*)&Bs[kk][tx * 4];
            float a_[4] = {av.x, av.y, av.z, av.w};
            float b_[4] = {bv.x, bv.y, bv.z, bv.w};
            #pragma unroll
            for (int i = 0; i < 4; ++i)
                #pragma unroll
                for (int j = 0; j < 4; ++j)
                    acc[i][j] += a_[i] * b_[j];
        }
    }
    int r = r0 + tx * 4;
    float bias[4];
    #pragma unroll
    for (int j = 0; j < 4; ++j) bias[j] = b_ih[r + j] + b_hh[r + j];
    // swizzled store: r..r+3 share gate and g, jj = 0..3 contiguous
    int gate = r >> 10;
    int gw   = (r & 1023) >> 2;
    #pragma unroll
    for (int i = 0; i < 4; ++i) {
        float4 o;
        o.x = acc[i][0] + bias[0]; o.y = acc[i][1] + bias[1];
        o.z = acc[i][2] + bias[2]; o.w = acc[i][3] + bias[3];
        *(float4*)(gates_x + (size_t)(t0 + ty * 4 + i) * 4096 + gw * 16 + gate * 4) = o;
    }
}

// ---------------------------------------------------------------------------
// Persistent recurrent kernel. 256 WGs x 256 threads, one per CU.
// Weights live in LDS (64 KB/WG, staged once) — R1/R2 proved the register
// allocator will not keep a 64-float array live across this loop (VGPR=88/52,
// scratch spill). Per step each thread re-reads its 256 B slice as 16
// ds_read_b128 ISSUED BEFORE the h-poll: lgkmcnt (DS) and vmcnt (poll) are
// independent, so the ~770-cyc LDS stream hides under the ~600-cyc L3 poll.
// asm memory clobbers fence the issue window (no LICM, no sinking).
// h_s layout: thread kq takes interleaved chunks h_s[i*16+kq] -> wave
// addresses 16 B apart = conflict-free (R2's kq*16+i pattern was 4-way
// same-bank, 264 conflict-cyc/step).
// h exchange: single-hop tag-in-word protocol, RELAXED agent atomics only.
__global__ __launch_bounds__(256, 1) void lstm_rec(const float* __restrict__ gates_x,
                                                   const float* __restrict__ W_r2,
                                                   float* __restrict__ h_all,
                                                   unsigned long long* h_msg) {
    const int g    = blockIdx.x;
    const int tid  = threadIdx.x;
    const int kq   = tid >> 4;      // k-slice selector
    const int wv   = tid >> 6;      // wave id 0..3
    const int lane = tid & 63;
    __shared__ float4 W_lds[16][256];   // [i][tid], 64 KB, lane-contiguous
    __shared__ float4 h_s[256];         // h_{s-1}; h_s[q] = h[4q..4q+3]
    __shared__ float  partial[4][20];   // [wave][row], padded

    // one-time stage: global (coalesced) -> LDS (lane-contiguous b128)
    {
        const float4* Wp = (const float4*)W_r2 + (size_t)g * 4096;
        #pragma unroll
        for (int i = 0; i < 16; ++i)
            W_lds[i][tid] = Wp[i * 256 + tid];
    }
    __syncthreads();

    float c = 0.f;               // cell state, meaningful in wave-0 lanes 0..3
    int budget = 4000000;        // anti-hang poll budget

    for (int s = 0; s < SEQL; ++s) {
        asm volatile("" ::: "memory");   // iteration fence: no LICM of W reads
        // 1) issue weight ds_reads (complete during the poll below)
        float4 w[16];
        #pragma unroll
        for (int i = 0; i < 16; ++i)
            w[i] = W_lds[i][tid];
        asm volatile("" ::: "memory");   // loads may not sink below this

        // 2) independent gx prefetch (wave-0 lanes 0..15 consume it later)
        float gx = 0.f;
        if (tid < 16)
            gx = gates_x[(size_t)s * 4096 + g * 16 + tid];

        // 3) poll h_{s-1}: thread tid owns msg quad tid (j = 4*tid..4*tid+3)
        {
            const unsigned long long* buf = h_msg + (size_t)(s & 1) * HD + tid * 4;
            const unsigned want = (unsigned)s;
            unsigned long long v0, v1, v2, v3;
            for (;;) {
                v0 = __hip_atomic_load(buf + 0, __ATOMIC_RELAXED, __HIP_MEMORY_SCOPE_AGENT);
                v1 = __hip_atomic_load(buf + 1, __ATOMIC_RELAXED, __HIP_MEMORY_SCOPE_AGENT);
                v2 = __hip_atomic_load(buf + 2, __ATOMIC_RELAXED, __HIP_MEMORY_SCOPE_AGENT);
                v3 = __hip_atomic_load(buf + 3, __ATOMIC_RELAXED, __HIP_MEMORY_SCOPE_AGENT);
                if ((unsigned)(v0 >> 32) == want && (unsigned)(v1 >> 32) == want &&
                    (unsigned)(v2 >> 32) == want && (unsigned)(v3 >> 32) == want) break;
                if (--budget < 0) break;
            }
            float4 hv;
            hv.x = __uint_as_float((unsigned)v0);
            hv.y = __uint_as_float((unsigned)v1);
            hv.z = __uint_as_float((unsigned)v2);
            hv.w = __uint_as_float((unsigned)v3);
            h_s[tid] = hv;
        }
        __syncthreads();

        // 4) matvec: thread (row=tid&15, kq) does 64 k's, interleaved chunks
        float a0 = 0.f, a1 = 0.f, a2 = 0.f, a3 = 0.f;
        #pragma unroll
        for (int i = 0; i < 16; ++i) {
            float4 h4 = h_s[i * 16 + kq];     // conflict-free: 16 B lane stride
            a0 += w[i].x * h4.x;
            a1 += w[i].y * h4.y;
            a2 += w[i].z * h4.z;
            a3 += w[i].w * h4.w;
        }
        float p = (a0 + a1) + (a2 + a3);
        // reduce kq within wave: lanes L and L^16 / L^32 share the same row
        p += __shfl_xor(p, 16, 64);
        p += __shfl_xor(p, 32, 64);
        if (lane < 16) partial[wv][lane] = p;   // per-wave row sums
        __syncthreads();

        // 5) wave-0 tail: final sum, activations, publish
        if (wv == 0) {
            int row = lane & 15;
            float sum = gx + ((partial[0][row] + partial[1][row])
                            + (partial[2][row] + partial[3][row]));
            // lanes 0..15 hold gv(row); gather the 4 gates of column jj=lane
            float vf = __shfl(sum, (lane & 3) + 4, 64);
            float vg = __shfl(sum, (lane & 3) + 8, 64);
            float vo = __shfl(sum, (lane & 3) + 12, 64);
            if (lane < 4) {
                float si = 1.f / (1.f + __expf(-sum));
                float sf = 1.f / (1.f + __expf(-vf));
                float so = 1.f / (1.f + __expf(-vo));
                float tg = 2.f / (1.f + __expf(-2.f * vg)) - 1.f;   // tanh
                c = sf * c + si * tg;
                float th = 2.f / (1.f + __expf(-2.f * c)) - 1.f;    // tanh
                float h = so * th;
                int j = g * JPW + lane;
                h_all[(size_t)s * HD + j] = h;
                unsigned long long m = ((unsigned long long)(unsigned)(s + 1) << 32)
                                     | (unsigned long long)__float_as_uint(h);
                __hip_atomic_store(h_msg + (size_t)((s + 1) & 1) * HD + j, m,
                                   __ATOMIC_RELAXED, __HIP_MEMORY_SCOPE_AGENT);
            }
        }
        // no trailing barrier: partial is next written only after the first
        // __syncthreads of iteration s+1
    }
}

// ---------------------------------------------------------------------------
// out[t][lab] = b_fc[lab] + sum_k h_all[t][k] * W_fc[lab][k]
__global__ __launch_bounds__(128) void fc_out(const float* __restrict__ h_all,
                                              const float* __restrict__ W_fc,
                                              const float* __restrict__ b_fc,
                                              float* __restrict__ out) {
    const int t = blockIdx.x;
    const int tid = threadIdx.x;
    __shared__ float4 h_s[256];
    const float4* hsrc = (const float4*)(h_all + (size_t)t * HD);
    h_s[tid] = hsrc[tid];
    h_s[tid + 128] = hsrc[tid + 128];
    __syncthreads();
    if (tid < NLAB) {
        float acc = b_fc[tid];
        const float4* wp = (const float4*)(W_fc + (size_t)tid * HD);
        #pragma unroll 8
        for (int k4 = 0; k4 < 256; ++k4) {
            float4 w = wp[k4];
            float4 h = h_s[k4];
            acc += w.x*h.x + w.y*h.y + w.z*h.z + w.w*h.w;
        }
        out[(size_t)t * NLAB + tid] = acc;
    }
}

// ---------------------------------------------------------------------------
extern "C" void kernel_launch(void* const* d_in, const int* in_sizes, int n_in,
                              void* d_out, int out_size, void* d_ws, size_t ws_size,
                              hipStream_t stream) {
    const float* x    = (const float*)d_in[0];
    const float* hi   = (const float*)d_in[1];
    const float* W_ih = (const float*)d_in[2];
    const float* W_hh = (const float*)d_in[3];
    const float* b_ih = (const float*)d_in[4];
    const float* b_hh = (const float*)d_in[5];
    const float* W_fc = (const float*)d_in[6];
    const float* b_fc = (const float*)d_in[7];
    float* out = (float*)d_out;

    char* ws = (char*)d_ws;
    unsigned long long* h_msg = (unsigned long long*)(ws + OFF_MSG);
    float* h_all   = (float*)(ws + OFF_HALL);
    float* gates_x = (float*)(ws + OFF_GATES);
    float* W_r2    = (float*)(ws + OFF_WR);

    // zero the msg buffer: h_{-1}=0 with tag 0 (ws is re-poisoned 0xAA each call)
    hipMemsetAsync(d_ws, 0, 16384, stream);

    prep_wr<<<4096, 256, 0, stream>>>(W_ih, W_hh, W_r2);

    dim3 gg(64, 8);
    gates_gemm<<<gg, 256, 0, stream>>>(x, hi, W_ih, b_ih, b_hh, gates_x);

    lstm_rec<<<NWG, 256, 0, stream>>>(gates_x, W_r2, h_all, h_msg);

    fc_out<<<SEQL, 128, 0, stream>>>(h_all, W_fc, b_fc, out);
}

// Round 5
// 1544.392 us; speedup vs baseline: 1.3537x; 1.3537x over previous
//
#include <hip/hip_runtime.h>
#include <math.h>

// Problem constants
#define HD    1024      // hidden size
#define SEQL  512       // sequence length
#define NLAB  122       // labels
#define NWG   128       // workgroups in persistent recurrent kernel
#define TPW   512       // threads per WG
#define JPW   8         // h-columns (j) per workgroup  (NWG*JPW == HD)

// Workspace layout (bytes). Total ≈ 27.3 MB.
#define OFF_MSG   ((size_t)0)          // h msg: 2*1024 u64 (tag<<32|h_bits)    = 16384 B
#define OFF_HALL  ((size_t)16384)      // h_all: 512*1024 fp32                  = 2097152 B
#define OFF_GATES ((size_t)2113536)    // gates_x: 512*4096 fp32 (swizzled)     = 8388608 B
#define OFF_WR    ((size_t)10502144)   // W_r2: 4096*1024 fp32 (swizzled)       = 16777216 B
// end = 27279360

typedef unsigned long long u64;

// ---------------------------------------------------------------------------
// Prep: W_r2 laid out [g][i][t] float4 (g<128, i<16, t<512) so lstm_rec WG g
// thread t stages LDS lane-contiguously and reads its 64-k slice as 16 b128.
//   t: row = t&31 (gate=row>>3, jj=row&7), kq = t>>5
//   w4[i] = W_r[R][k..k+3], k = kq*64 + i*4, R = gate*1024 + g*8 + jj
//   W_r[R][k] = W_ih[R][4096+k] + W_hh[R][k]
__global__ __launch_bounds__(256) void prep_wr(const float* __restrict__ W_ih,
                                               const float* __restrict__ W_hh,
                                               float* __restrict__ W_r2) {
    int o = blockIdx.x * 256 + threadIdx.x;   // output float4 index, < 1048576
    int g   = o >> 13;            // 16*512 float4 per g
    int i   = (o >> 9) & 15;
    int t   = o & 511;
    int row = t & 31;
    int kq  = t >> 5;
    int gate = row >> 3;
    int jj   = row & 7;
    int R = (gate << 10) + (g << 3) + jj;
    int k = (kq << 6) + (i << 2);
    float4 wa = *(const float4*)(W_ih + (size_t)R * 5120 + 4096 + k);
    float4 wb = *(const float4*)(W_hh + (size_t)R * 1024 + k);
    float4 out;
    out.x = wa.x + wb.x; out.y = wa.y + wb.y; out.z = wa.z + wb.z; out.w = wa.w + wb.w;
    *(float4*)(W_r2 + (size_t)o * 4) = out;
}

// ---------------------------------------------------------------------------
// gates_x[t][g*32 + gate*8 + jj] = b[r] + sum_k feats[t][k] * W_ih[r][k]
//   r = gate*1024 + g*8 + jj  (swizzled so WG g's 32 values/step are two
//   contiguous 64 B lines). feats = concat(x, hi). 64x64 tile, BK=16, fp32.
__global__ __launch_bounds__(256) void gates_gemm(const float* __restrict__ x,
                                                  const float* __restrict__ hi,
                                                  const float* __restrict__ W_ih,
                                                  const float* __restrict__ b_ih,
                                                  const float* __restrict__ b_hh,
                                                  float* __restrict__ gates_x) {
    __shared__ float As[16][68];
    __shared__ float Bs[16][68];
    const int tid = threadIdx.x;
    const int r0 = blockIdx.x * 64;
    const int t0 = blockIdx.y * 64;
    const int tx = tid & 15, ty = tid >> 4;
    const int l   = tid & 63;
    const int kq4 = tid >> 6;

    float acc[4][4] = {};
    for (int kb = 0; kb < 4096; kb += 16) {
        int k = kb + kq4 * 4;
        const float* asrc = (k < 2048) ? (x  + (size_t)(t0 + l) * 2048 + k)
                                       : (hi + (size_t)(t0 + l) * 2048 + (k - 2048));
        float4 a4 = *(const float4*)asrc;
        float4 b4 = *(const float4*)(W_ih + (size_t)(r0 + l) * 5120 + k);
        __syncthreads();
        As[kq4 * 4 + 0][l] = a4.x; As[kq4 * 4 + 1][l] = a4.y;
        As[kq4 * 4 + 2][l] = a4.z; As[kq4 * 4 + 3][l] = a4.w;
        Bs[kq4 * 4 + 0][l] = b4.x; Bs[kq4 * 4 + 1][l] = b4.y;
        Bs[kq4 * 4 + 2][l] = b4.z; Bs[kq4 * 4 + 3][l] = b4.w;
        __syncthreads();
        #pragma unroll
        for (int kk = 0; kk < 16; ++kk) {
            float4 av = *(const float4*)&As[kk][ty * 4];
            float4 bv = *(const float4*)&Bs[kk][tx * 4];
            float a_[4] = {av.x, av.y, av.z, av.w};
            float b_[4] = {bv.x, bv.y, bv.z, bv.w};
            #pragma unroll
            for (int i = 0; i < 4; ++i)
                #pragma unroll
                for (int j = 0; j < 4; ++j)
                    acc[i][j] += a_[i] * b_[j];
        }
    }
    int r = r0 + tx * 4;          // 4 consecutive rows: same gate, same g, jj+0..3
    float bias[4];
    #pragma unroll
    for (int j = 0; j < 4; ++j) bias[j] = b_ih[r + j] + b_hh[r + j];
    int gate = r >> 10;
    int g    = (r & 1023) >> 3;
    int jj   = r & 7;             // 0 or 4
    int sidx = g * 32 + gate * 8 + jj;
    #pragma unroll
    for (int i = 0; i < 4; ++i) {
        float4 o;
        o.x = acc[i][0] + bias[0]; o.y = acc[i][1] + bias[1];
        o.z = acc[i][2] + bias[2]; o.w = acc[i][3] + bias[3];
        *(float4*)(gates_x + (size_t)(t0 + ty * 4 + i) * 4096 + sidx) = o;
    }
}

// ---------------------------------------------------------------------------
// Persistent recurrent kernel. 128 WGs x 512 threads (R4: halved the
// synchronization domain — R3's 256-consumer poll storm kept 2 MB/sweep of
// L2-bypass traffic in flight; FETCH_SIZE ~41 MB of pure polling).
// WG g owns columns j = g*8..g*8+7 (32 gate rows). Thread: row = tid&31,
// kq = tid>>5 (64-k slice). Weights in LDS (128 KB), prefetched to regs
// before the poll (lgkm hides under vmcnt).
// h exchange: tag-in-word (tag s+1 <<32 | f32 bits), RELAXED agent atomics,
// 2 contiguous u64 per thread, staggered double-sample poll.
__global__ __launch_bounds__(512, 1) void lstm_rec(const float* __restrict__ gates_x,
                                                   const float* __restrict__ W_r2,
                                                   float* __restrict__ h_all,
                                                   u64* h_msg) {
    const int g   = blockIdx.x;
    const int tid = threadIdx.x;
    const int row = tid & 31;    // gate = row>>3, jj = row&7
    const int kq  = tid >> 5;    // k-slice [kq*64, kq*64+64)
    __shared__ float4 W_lds[16][TPW];   // 128 KB, lane-contiguous
    __shared__ float4 h_s4[256];        // h_{s-1}; h_s4[q] = h[4q..4q+3]
    __shared__ float  partial[8][36];   // [wave][row]
    float* h_sf = (float*)h_s4;

    // one-time stage: global (coalesced) -> LDS
    {
        const float4* Wp = (const float4*)W_r2 + (size_t)g * 8192;
        #pragma unroll
        for (int i = 0; i < 16; ++i)
            W_lds[i][tid] = Wp[i * TPW + tid];
    }
    __syncthreads();

    float c = 0.f;               // cell state, meaningful in tid<8
    int budget = 4000000;        // anti-hang poll budget

    for (int s = 0; s < SEQL; ++s) {
        asm volatile("" ::: "memory");
        // 1) weight ds_reads issue now, complete under the poll (lgkm vs vm)
        float4 w[16];
        #pragma unroll
        for (int i = 0; i < 16; ++i)
            w[i] = W_lds[i][tid];
        asm volatile("" ::: "memory");

        // 2) independent gx prefetch (wave-0 lanes 0..31 consume later)
        float gx = 0.f;
        if (tid < 32)
            gx = gates_x[(size_t)s * 4096 + g * 32 + tid];

        // 3) poll h_{s-1}: thread owns msg words 2tid, 2tid+1.
        //    Staggered double-sample: two load pairs in flight halves the
        //    detection quantum; sample B issued after A is valid whenever
        //    A's tags were already observed complete (monotone MALL order).
        {
            const u64* buf = h_msg + (size_t)(s & 1) * HD + tid * 2;
            const unsigned want = (unsigned)s;
            u64 r0, r1;
            for (;;) {
                u64 a0 = __hip_atomic_load(buf + 0, __ATOMIC_RELAXED, __HIP_MEMORY_SCOPE_AGENT);
                u64 a1 = __hip_atomic_load(buf + 1, __ATOMIC_RELAXED, __HIP_MEMORY_SCOPE_AGENT);
                u64 b0 = __hip_atomic_load(buf + 0, __ATOMIC_RELAXED, __HIP_MEMORY_SCOPE_AGENT);
                u64 b1 = __hip_atomic_load(buf + 1, __ATOMIC_RELAXED, __HIP_MEMORY_SCOPE_AGENT);
                if ((unsigned)(a0 >> 32) == want && (unsigned)(a1 >> 32) == want) {
                    r0 = a0; r1 = a1; break;
                }
                if ((unsigned)(b0 >> 32) == want && (unsigned)(b1 >> 32) == want) {
                    r0 = b0; r1 = b1; break;
                }
                if (--budget < 0) { r0 = b0; r1 = b1; break; }
            }
            h_sf[2 * tid + 0] = __uint_as_float((unsigned)r0);
            h_sf[2 * tid + 1] = __uint_as_float((unsigned)r1);
        }
        __syncthreads();

        // 4) matvec: 1 row x 64 k per thread; h broadcast-friendly (32 lanes
        //    share each address, 2 distinct addrs/instr -> free 2-way)
        float a0 = 0.f, a1 = 0.f, a2 = 0.f, a3 = 0.f;
        #pragma unroll
        for (int i = 0; i < 16; ++i) {
            float4 h4 = h_s4[kq * 16 + i];
            a0 += w[i].x * h4.x;
            a1 += w[i].y * h4.y;
            a2 += w[i].z * h4.z;
            a3 += w[i].w * h4.w;
        }
        float p = (a0 + a1) + (a2 + a3);
        p += __shfl_xor(p, 32, 64);          // fold the wave's two kq halves
        if ((tid & 32) == 0)
            partial[tid >> 6][row] = p;      // lanes 0..31 of each wave
        __syncthreads();

        // 5) wave-0 tail: final 8-way sum, activations, publish (one 64B line)
        if (tid < 32) {
            float sum = gx;
            #pragma unroll
            for (int q = 0; q < 8; ++q) sum += partial[q][tid];
            int jj = tid & 7;
            float vf = __shfl(sum,  8 + jj, 64);
            float vg = __shfl(sum, 16 + jj, 64);
            float vo = __shfl(sum, 24 + jj, 64);
            if (tid < 8) {
                float si = 1.f / (1.f + __expf(-sum));
                float sf = 1.f / (1.f + __expf(-vf));
                float so = 1.f / (1.f + __expf(-vo));
                float tg = 2.f / (1.f + __expf(-2.f * vg)) - 1.f;   // tanh
                c = sf * c + si * tg;
                float th = 2.f / (1.f + __expf(-2.f * c)) - 1.f;    // tanh
                float h = so * th;
                int j = g * JPW + tid;
                h_all[(size_t)s * HD + j] = h;
                u64 m = ((u64)(unsigned)(s + 1) << 32)
                      | (u64)__float_as_uint(h);
                __hip_atomic_store(h_msg + (size_t)((s + 1) & 1) * HD + j, m,
                                   __ATOMIC_RELAXED, __HIP_MEMORY_SCOPE_AGENT);
            }
        }
        // no trailing barrier: partial[] is next written only after the
        // first two __syncthreads of iteration s+1
    }
}

// ---------------------------------------------------------------------------
// out[t][lab] = b_fc[lab] + sum_k h_all[t][k] * W_fc[lab][k]
__global__ __launch_bounds__(128) void fc_out(const float* __restrict__ h_all,
                                              const float* __restrict__ W_fc,
                                              const float* __restrict__ b_fc,
                                              float* __restrict__ out) {
    const int t = blockIdx.x;
    const int tid = threadIdx.x;
    __shared__ float4 h_s[256];
    const float4* hsrc = (const float4*)(h_all + (size_t)t * HD);
    h_s[tid] = hsrc[tid];
    h_s[tid + 128] = hsrc[tid + 128];
    __syncthreads();
    if (tid < NLAB) {
        float acc = b_fc[tid];
        const float4* wp = (const float4*)(W_fc + (size_t)tid * HD);
        #pragma unroll 8
        for (int k4 = 0; k4 < 256; ++k4) {
            float4 w = wp[k4];
            float4 h = h_s[k4];
            acc += w.x*h.x + w.y*h.y + w.z*h.z + w.w*h.w;
        }
        out[(size_t)t * NLAB + tid] = acc;
    }
}

// ---------------------------------------------------------------------------
extern "C" void kernel_launch(void* const* d_in, const int* in_sizes, int n_in,
                              void* d_out, int out_size, void* d_ws, size_t ws_size,
                              hipStream_t stream) {
    const float* x    = (const float*)d_in[0];
    const float* hi   = (const float*)d_in[1];
    const float* W_ih = (const float*)d_in[2];
    const float* W_hh = (const float*)d_in[3];
    const float* b_ih = (const float*)d_in[4];
    const float* b_hh = (const float*)d_in[5];
    const float* W_fc = (const float*)d_in[6];
    const float* b_fc = (const float*)d_in[7];
    float* out = (float*)d_out;

    char* ws = (char*)d_ws;
    u64*   h_msg   = (u64*)(ws + OFF_MSG);
    float* h_all   = (float*)(ws + OFF_HALL);
    float* gates_x = (float*)(ws + OFF_GATES);
    float* W_r2    = (float*)(ws + OFF_WR);

    // zero the msg buffer: h_{-1}=0 with tag 0 (ws is re-poisoned 0xAA each call)
    hipMemsetAsync(d_ws, 0, 16384, stream);

    prep_wr<<<4096, 256, 0, stream>>>(W_ih, W_hh, W_r2);

    dim3 gg(64, 8);
    gates_gemm<<<gg, 256, 0, stream>>>(x, hi, W_ih, b_ih, b_hh, gates_x);

    lstm_rec<<<NWG, TPW, 0, stream>>>(gates_x, W_r2, h_all, h_msg);

    fc_out<<<SEQL, 128, 0, stream>>>(h_all, W_fc, b_fc, out);
}